// Round 13
// baseline (150.572 us; speedup 1.0000x reference)
//
#include <hip/hip_runtime.h>

typedef __attribute__((ext_vector_type(4))) float f32x4;
typedef __attribute__((ext_vector_type(8))) short short8;
typedef __attribute__((ext_vector_type(2))) unsigned u32x2;

typedef __attribute__((address_space(1))) const void gv_t;
typedef __attribute__((address_space(3))) void lv_t;

__device__ __forceinline__ ushort f2bf(float f) {
  union { float f; unsigned u; } v; v.f = f;
  unsigned r = v.u + 0x7fffu + ((v.u >> 16) & 1u);
  return (ushort)(r >> 16);
}
__device__ __forceinline__ float bf2f(ushort u) {
  union { unsigned u; float f; } v; v.u = ((unsigned)u) << 16;
  return v.f;
}

// DPP lane-permute on the VALU pipe (not DS)
template<int CTRL>
__device__ __forceinline__ float dppf(float x) {
  union { float f; int i; } u; u.f = x;
  u.i = __builtin_amdgcn_update_dpp(0, u.i, CTRL, 0xf, 0xf, true);
  return u.f;
}
__device__ __forceinline__ float rsum16(float x) {
  x += dppf<0xB1>(x);
  x += dppf<0x4E>(x);
  x += dppf<0x124>(x);
  x += dppf<0x128>(x);
  return x;
}

// ---------------- fused prep: all bf16 conversions + bias copy, one launch ----
__global__ void k_prep(const float* __restrict__ hidden, const float* __restrict__ Wq,
                       const float* __restrict__ Wk, const float* __restrict__ Wv,
                       const float* __restrict__ dist, const float* __restrict__ bq,
                       const float* __restrict__ bk, const float* __restrict__ bv,
                       ushort* __restrict__ Hbf, ushort* __restrict__ Wqkv,
                       ushort* __restrict__ Ebf, float* __restrict__ Bqkv) {
  int i = blockIdx.x * blockDim.x + threadIdx.x;
  const float* src; ushort* dst; int o;
  if (i < 1048576)      { src = hidden; o = i;            dst = Hbf; }
  else if (i < 1310720) { src = Wq;   o = i - 1048576;    dst = Wqkv; }
  else if (i < 1572864) { src = Wk;   o = i - 1310720;    dst = Wqkv + 1048576; }
  else if (i < 1835008) { src = Wv;   o = i - 1572864;    dst = Wqkv + 2097152; }
  else if (i < 1867760) { src = dist; o = i - 1835008;    dst = Ebf; }
  else if (i < 1868528) {
    int ib = i - 1867760;
    const float* bs = ib < 256 ? bq : (ib < 512 ? bk : bv);
    reinterpret_cast<float4*>(Bqkv)[ib] = reinterpret_cast<const float4*>(bs)[ib & 255];
    return;
  } else return;
  float4 v = reinterpret_cast<const float4*>(src)[o];
  ushort4 u;
  u.x = f2bf(v.x); u.y = f2bf(v.y); u.z = f2bf(v.z); u.w = f2bf(v.w);
  reinterpret_cast<ushort4*>(dst)[o] = u;
}

// ---------------- fused QKV projection GEMM + inline V-transpose epilogue -----
// Q/K columns (n0 < 2048) -> QKV row-major. V columns (n0 >= 2048) -> VT
// [(b*16+h)*64 + d][l] directly (transposed), replacing the k_vt kernel.
__global__ __launch_bounds__(256) void k_gemm_qkv(
    const ushort* __restrict__ A, const ushort* __restrict__ W,
    const float* __restrict__ bias, ushort* __restrict__ C,
    ushort* __restrict__ VT)
{
  __shared__ __align__(16) ushort As[128 * 32];
  __shared__ __align__(16) ushort Bs[128 * 32];
  // XCD-aware swizzle: 768 blocks, 8 XCDs, 96 per XCD (768%8==0, bijective)
  int linear = blockIdx.x + blockIdx.y * 24;
  int swzb = (linear & 7) * 96 + (linear >> 3);
  const int n0 = (swzb % 24) * 128;
  const int m0 = (swzb / 24) * 128;
  const int tid = threadIdx.x;
  const int w = tid >> 6, lane = tid & 63;
  const int wr = (w >> 1) * 64, wc = (w & 1) * 64;
  const int lr = lane & 15, lk = (lane >> 4) * 8;

  f32x4 acc[4][4] = {};

  for (int k0 = 0; k0 < 1024; k0 += 32) {
    __syncthreads();
#pragma unroll
    for (int inst = 0; inst < 2; ++inst) {
      int chunk = w * 128 + inst * 64 + lane;
      int row = chunk >> 2, c8 = (chunk & 3) * 8;
      __builtin_amdgcn_global_load_lds(
          (gv_t*)(A + (size_t)(m0 + row) * 1024 + k0 + c8),
          (lv_t*)(As + (size_t)(w * 128 + inst * 64) * 8), 16, 0, 0);
      __builtin_amdgcn_global_load_lds(
          (gv_t*)(W + (size_t)(n0 + row) * 1024 + k0 + c8),
          (lv_t*)(Bs + (size_t)(w * 128 + inst * 64) * 8), 16, 0, 0);
    }
    __syncthreads();
    short8 af[4], bfr[4];
#pragma unroll
    for (int t = 0; t < 4; ++t) {
      af[t]  = *reinterpret_cast<const short8*>(As + (wr + t * 16 + lr) * 32 + lk);
      bfr[t] = *reinterpret_cast<const short8*>(Bs + (wc + t * 16 + lr) * 32 + lk);
    }
#pragma unroll
    for (int mt = 0; mt < 4; ++mt)
#pragma unroll
      for (int nt = 0; nt < 4; ++nt)
        acc[mt][nt] = __builtin_amdgcn_mfma_f32_16x16x32_bf16(af[mt], bfr[nt], acc[mt][nt], 0, 0, 0);
  }

  float bv[4];
#pragma unroll
  for (int nt = 0; nt < 4; ++nt) bv[nt] = bias[n0 + wc + nt * 16 + lr];

  if (n0 < 2048) {
    // Q/K region: row-major into QKV
#pragma unroll
    for (int mt = 0; mt < 4; ++mt)
#pragma unroll
      for (int nt = 0; nt < 4; ++nt)
#pragma unroll
        for (int j = 0; j < 4; ++j) {
          int row = m0 + wr + mt * 16 + (lane >> 4) * 4 + j;
          int col = n0 + wc + nt * 16 + lr;
          C[(size_t)row * 3072 + col] = f2bf(acc[mt][nt][j] + bv[nt]);
        }
  } else {
    // V region: write transposed directly into VT[(b*16+h)*64 + d][l]
#pragma unroll
    for (int mt = 0; mt < 4; ++mt) {
      int lg = m0 + wr + mt * 16 + (lane >> 4) * 4;  // 4 consecutive rows l..l+3
      int b = lg >> 10, l = lg & 1023;
#pragma unroll
      for (int nt = 0; nt < 4; ++nt) {
        int col = n0 + wc + nt * 16 + lr;
        int h = (col - 2048) >> 6, d = col & 63;
        ushort4 pk;
        pk.x = f2bf(acc[mt][nt][0] + bv[nt]);
        pk.y = f2bf(acc[mt][nt][1] + bv[nt]);
        pk.z = f2bf(acc[mt][nt][2] + bv[nt]);
        pk.w = f2bf(acc[mt][nt][3] + bv[nt]);
        *reinterpret_cast<ushort4*>(VT + (size_t)((b * 16 + h) * 64 + d) * 1024 + l) = pk;
      }
    }
  }
}

// ---------------- fused attention, 2 l-tiles/block, 8 waves -------------------
// Round-12 kernel, unchanged (104 us): T2 tiles {w,w+4} reuse t1loc E frags,
// fixed-max softmax via exp2, XCD swizzle, DPP reductions, conflicts=0.
__global__ __launch_bounds__(512, 4) void k_attn(
    const ushort* __restrict__ QKV, const ushort* __restrict__ VTg,
    const ushort* __restrict__ E, const float* __restrict__ mask,
    float* __restrict__ out)
{
  __shared__ __align__(16) ushort Kl[64 * 64];     //  8 KB
  __shared__ __align__(16) ushort Vl[64 * 64];     //  8 KB
  __shared__ __align__(16) ushort El[256 * 64];    // 32 KB circular E window
  __shared__ __align__(16) ushort T2s[64 * 196];   // 24.5 KB; first 8192 elems alias P

  // XCD-aware swizzle: 512 blocks, 8 XCDs -> each XCD gets 8 full (b,h) panels
  int linear = blockIdx.x + (blockIdx.y << 3) + (blockIdx.z << 7);
  int swzb = (linear & 7) * 64 + (linear >> 3);
  const int lt = swzb & 7, h = (swzb >> 3) & 15, b = swzb >> 7;

  const int bh = b * 16 + h;
  const int l0 = lt * 128;
  const int tid = threadIdx.x;
  const int w = tid >> 6, lane = tid & 63;
  const int g = lane >> 4, m = lane & 15, g4 = g * 4;
  const int rsub = lane >> 3, csub = lane & 7;

  const ushort* Qg = QKV;
  const ushort* Kg = QKV + 1024;
  const float* maskrow = mask + b * 1024;

  // Q fragments (reused all r-tiles)
  short8 qf0, qf1;
  {
    const size_t qoff = (size_t)(b * 1024 + l0 + w * 16 + m) * 3072 + h * 64;
    qf0 = *reinterpret_cast<const short8*>(Qg + qoff + g * 8);
    qf1 = *reinterpret_cast<const short8*>(Qg + qoff + 32 + g * 8);
  }

  // hoisted T1-gather constants (round-3/4 verified)
  int srcl[4], bsel[4];
#pragma unroll
  for (int j = 0; j < 4; ++j) {
    int x = (g4 + j + 63 - m) & 15;
    srcl[j] = (lane & 48) | x;
    bsel[j] = (g4 + j) > x;
  }
  // T2 gather: elem addr = A0 + 3120*ct + j   (addr = (16ct+m)*196 + dd)
  const int A0 = 195 * m + 16 * w + g4 + 63;

  // ---- prologue staging: K tile 0, E window rows 0..191
  {
    int kr = w * 8 + rsub;
    __builtin_amdgcn_global_load_lds(
        (gv_t*)(Kg + (size_t)(b * 1024 + kr) * 3072 + h * 64 + ((csub ^ (kr & 7)) << 3)),
        (lv_t*)(Kl + w * 512), 16, 0, 0);
#pragma unroll
    for (int i = 0; i < 3; ++i) {
      int li = w * 3 + i;
      int er = li * 8 + rsub;
      int p = l0 + 960 + er; if (p > 2046) p = 2046;  // clamped row never gathered
      __builtin_amdgcn_global_load_lds(
          (gv_t*)(E + (size_t)p * 64 + ((csub ^ (er & 7)) << 3)),
          (lv_t*)(El + li * 512), 16, 0, 0);
    }
  }

  f32x4 o_[4] = {};
  float s_[4];
#pragma unroll
  for (int j = 0; j < 4; ++j) s_[j] = 0.f;

  int rot = 0;

  for (int rt = 0; rt < 16; ++rt) {
    const int r0 = rt * 64;
    __syncthreads();  // B1: K/E(cur) staged visible; Vl free (prev PV done)

    // V stage (cur) — drains at B2
    {
      int dr = w * 8 + rsub;
      __builtin_amdgcn_global_load_lds(
          (gv_t*)(VTg + (size_t)(bh * 64 + dr) * 1024 + r0 + ((csub ^ (dr & 7)) << 3)),
          (lv_t*)(Vl + w * 512), 16, 0, 0);
    }

    // E fragments for window tiles w (ea0) and w+4 (ea1); shared by T1 AND T2
    short8 ea0[2], ea1[2];
    {
      int row = w * 16 + m, phys = (row + rot) & 255;
      ea0[0] = *reinterpret_cast<const short8*>(El + phys * 64 + ((g ^ (row & 7)) << 3));
      ea0[1] = *reinterpret_cast<const short8*>(El + phys * 64 + (((g + 4) ^ (row & 7)) << 3));
    }
    {
      int row = (w + 4) * 16 + m, phys = (row + rot) & 255;
      ea1[0] = *reinterpret_cast<const short8*>(El + phys * 64 + ((g ^ (row & 7)) << 3));
      ea1[1] = *reinterpret_cast<const short8*>(El + phys * 64 + (((g + 4) ^ (row & 7)) << 3));
    }

    // QK^T + T2 (transposed-output) per f-tile.
    // T2 tiles: all waves -> tile w+4 (from ea1); waves 0-3 also tile w (ea0).
    f32x4 sc[4];
#pragma unroll
    for (int ft = 0; ft < 4; ++ft) {
      int kr = ft * 16 + m;
      short8 kb0 = *reinterpret_cast<const short8*>(Kl + kr * 64 + ((g ^ (kr & 7)) << 3));
      short8 kb1 = *reinterpret_cast<const short8*>(Kl + kr * 64 + (((g + 4) ^ (kr & 7)) << 3));
      f32x4 z = {0.f, 0.f, 0.f, 0.f};
      sc[ft] = __builtin_amdgcn_mfma_f32_16x16x32_bf16(qf1, kb1,
               __builtin_amdgcn_mfma_f32_16x16x32_bf16(qf0, kb0, z, 0, 0, 0), 0, 0, 0);
      {
        f32x4 t2 = __builtin_amdgcn_mfma_f32_16x16x32_bf16(ea1[1], kb1,
                   __builtin_amdgcn_mfma_f32_16x16x32_bf16(ea1[0], kb0, z, 0, 0, 0), 0, 0, 0);
        u32x2 pk;
        pk[0] = (unsigned)f2bf(t2[0]) | ((unsigned)f2bf(t2[1]) << 16);
        pk[1] = (unsigned)f2bf(t2[2]) | ((unsigned)f2bf(t2[3]) << 16);
        *reinterpret_cast<u32x2*>(T2s + (ft * 16 + m) * 196 + (w + 4) * 16 + g4) = pk;
      }
      if (w < 4) {
        f32x4 t2 = __builtin_amdgcn_mfma_f32_16x16x32_bf16(ea0[1], kb1,
                   __builtin_amdgcn_mfma_f32_16x16x32_bf16(ea0[0], kb0, z, 0, 0, 0), 0, 0, 0);
        u32x2 pk;
        pk[0] = (unsigned)f2bf(t2[0]) | ((unsigned)f2bf(t2[1]) << 16);
        pk[1] = (unsigned)f2bf(t2[2]) | ((unsigned)f2bf(t2[3]) << 16);
        *reinterpret_cast<u32x2*>(T2s + (ft * 16 + m) * 196 + w * 16 + g4) = pk;
      }
    }

    // T1 local-window frags (dd in [16w, 16w+79)); tiles 0,4 reuse ea0/ea1
    f32x4 t1loc[5];
    {
      f32x4 z = {0.f, 0.f, 0.f, 0.f};
      t1loc[0] = __builtin_amdgcn_mfma_f32_16x16x32_bf16(qf1, ea0[1],
                 __builtin_amdgcn_mfma_f32_16x16x32_bf16(qf0, ea0[0], z, 0, 0, 0), 0, 0, 0);
      t1loc[4] = __builtin_amdgcn_mfma_f32_16x16x32_bf16(qf1, ea1[1],
                 __builtin_amdgcn_mfma_f32_16x16x32_bf16(qf0, ea1[0], z, 0, 0, 0), 0, 0, 0);
    }
#pragma unroll
    for (int lti = 1; lti < 4; ++lti) {
      int row = (w + lti) * 16 + m, phys = (row + rot) & 255;
      short8 e0 = *reinterpret_cast<const short8*>(El + phys * 64 + ((g ^ (row & 7)) << 3));
      short8 e1 = *reinterpret_cast<const short8*>(El + phys * 64 + (((g + 4) ^ (row & 7)) << 3));
      f32x4 z = {0.f, 0.f, 0.f, 0.f};
      t1loc[lti] = __builtin_amdgcn_mfma_f32_16x16x32_bf16(qf1, e1,
                   __builtin_amdgcn_mfma_f32_16x16x32_bf16(qf0, e0, z, 0, 0, 0), 0, 0, 0);
    }

    __syncthreads();  // B2: T2s + Vl visible; Kl/El phase-1 readers done

    // stage next K tile + next 64 E rows (dest rows disjoint from live window)
    if (rt < 15) {
      int kr = w * 8 + rsub;
      __builtin_amdgcn_global_load_lds(
          (gv_t*)(Kg + (size_t)(b * 1024 + r0 + 64 + kr) * 3072 + h * 64 + ((csub ^ (kr & 7)) << 3)),
          (lv_t*)(Kl + w * 512), 16, 0, 0);
      int X = (rot + 192) & 255;
      int er = w * 8 + rsub;
      int p = l0 + 960 - 64 * (rt + 1) + er;  // in [0,1855], no clamp needed
      __builtin_amdgcn_global_load_lds(
          (gv_t*)(E + (size_t)p * 64 + ((csub ^ (er & 7)) << 3)),
          (lv_t*)(El + (X + w * 8) * 64), 16, 0, 0);
    }

    // S assembly + fixed-max softmax via exp2:
    // P = exp2((sc+t1+t2)*0.125*log2e + mk*log2e)
    float sv[4][4];
    const float SCL = 0.18033688f;  // 0.125 * log2(e)
#pragma unroll
    for (int ct = 0; ct < 4; ++ct) {
      float mkl = maskrow[r0 + ct * 16 + m] * 1.4426950f;
#pragma unroll
      for (int j = 0; j < 4; ++j) {
        float t2v = bf2f(T2s[A0 + 3120 * ct + j]);
        float val = bsel[j] ? t1loc[4 - ct][j] : t1loc[3 - ct][j];
        float t1v = __shfl(val, srcl[j]);
        sv[ct][j] = __builtin_amdgcn_exp2f((sc[ct][j] + t1v + t2v) * SCL + mkl);
      }
    }
#pragma unroll
    for (int j = 0; j < 4; ++j) {
      float rs = sv[0][j] + sv[1][j] + sv[2][j] + sv[3][j];
      rs = rsum16(rs);
      s_[j] += rs;
    }

    __syncthreads();  // B2.5: all waves' T2s gather reads complete — alias safe

    // P -> LDS (alias over T2s), row-major [e][f] with chunk XOR swizzle
    ushort* Pp = (ushort*)T2s;
#pragma unroll
    for (int ct = 0; ct < 4; ++ct)
#pragma unroll
      for (int j = 0; j < 4; ++j) {
        int e = g4 + j;
        int f = ct * 16 + m;
        Pp[w * 1024 + e * 64 + ((((f >> 3) ^ (e & 7)) << 3) | (f & 7))] = f2bf(sv[ct][j]);
      }

    // PV: A = P rows (b128), B = V^T rows (b128)
    {
      short8 pf0 = *reinterpret_cast<const short8*>(Pp + w * 1024 + m * 64 + ((g ^ (m & 7)) << 3));
      short8 pf1 = *reinterpret_cast<const short8*>(Pp + w * 1024 + m * 64 + (((g + 4) ^ (m & 7)) << 3));
#pragma unroll
      for (int vt = 0; vt < 4; ++vt) {
        int dr = vt * 16 + m;
        short8 vb0 = *reinterpret_cast<const short8*>(Vl + dr * 64 + ((g ^ (dr & 7)) << 3));
        short8 vb1 = *reinterpret_cast<const short8*>(Vl + dr * 64 + (((g + 4) ^ (dr & 7)) << 3));
        o_[vt] = __builtin_amdgcn_mfma_f32_16x16x32_bf16(pf0, vb0, o_[vt], 0, 0, 0);
        o_[vt] = __builtin_amdgcn_mfma_f32_16x16x32_bf16(pf1, vb1, o_[vt], 0, 0, 0);
      }
    }

    rot = (rot + 192) & 255;
  }

  // epilogue: O / s
#pragma unroll
  for (int j = 0; j < 4; ++j) {
    float inv = 1.0f / s_[j];
    int row = b * 1024 + l0 + w * 16 + g4 + j;
#pragma unroll
    for (int vt = 0; vt < 4; ++vt)
      out[(size_t)row * 1024 + h * 64 + vt * 16 + m] = o_[vt][j] * inv;
  }
}

// ---------------- host launch ----------------
extern "C" void kernel_launch(void* const* d_in, const int* in_sizes, int n_in,
                              void* d_out, int out_size, void* d_ws, size_t ws_size,
                              hipStream_t stream) {
  const float* hidden = (const float*)d_in[0];
  const float* mask   = (const float*)d_in[1];
  const float* Wq = (const float*)d_in[2];
  const float* bq = (const float*)d_in[3];
  const float* Wk = (const float*)d_in[4];
  const float* bk = (const float*)d_in[5];
  const float* Wv = (const float*)d_in[6];
  const float* bv = (const float*)d_in[7];
  const float* dist = (const float*)d_in[8];
  float* out = (float*)d_out;

  char* ws = (char*)d_ws;
  ushort* Hbf  = (ushort*)(ws);                                      //  8,388,608
  ushort* Wqkv = (ushort*)(ws + 8388608);                            //  6,291,456
  float*  Bqkv = (float*) (ws + 8388608 + 6291456);                  //     16,384
  ushort* Ebf  = (ushort*)(ws + 8388608 + 6291456 + 16384);          //    262,144
  ushort* QKV  = (ushort*)(ws + 8388608 + 6291456 + 16384 + 262144); // 25,165,824
  // VT lives in the QKV V-slice's former global footprint: use a dedicated
  // region after QKV (ws is 40.2+ MB; VT = 8,388,608 bytes)
  ushort* VT   = (ushort*)(ws + 8388608 + 6291456 + 16384 + 262144 + 25165824);

  k_prep<<<7299, 256, 0, stream>>>(hidden, Wq, Wk, Wv, dist, bq, bk, bv,
                                   Hbf, Wqkv, Ebf, Bqkv);
  k_gemm_qkv<<<dim3(24, 32), 256, 0, stream>>>(Hbf, Wqkv, Bqkv, QKV, VT);
  k_attn<<<dim3(8, 16, 4), 512, 0, stream>>>(QKV, VT, Ebf, mask, out);
}

// Round 15
// 138.099 us; speedup vs baseline: 1.0903x; 1.0903x over previous
//
#include <hip/hip_runtime.h>

typedef __attribute__((ext_vector_type(4))) float f32x4;
typedef __attribute__((ext_vector_type(8))) short short8;
typedef __attribute__((ext_vector_type(2))) unsigned u32x2;

typedef __attribute__((address_space(1))) const void gv_t;
typedef __attribute__((address_space(3))) void lv_t;

__device__ __forceinline__ ushort f2bf(float f) {
  union { float f; unsigned u; } v; v.f = f;
  unsigned r = v.u + 0x7fffu + ((v.u >> 16) & 1u);
  return (ushort)(r >> 16);
}
__device__ __forceinline__ float bf2f(ushort u) {
  union { unsigned u; float f; } v; v.u = ((unsigned)u) << 16;
  return v.f;
}

// DPP lane-permute on the VALU pipe (not DS)
template<int CTRL>
__device__ __forceinline__ float dppf(float x) {
  union { float f; int i; } u; u.f = x;
  u.i = __builtin_amdgcn_update_dpp(0, u.i, CTRL, 0xf, 0xf, true);
  return u.f;
}
__device__ __forceinline__ float rsum16(float x) {
  x += dppf<0xB1>(x);
  x += dppf<0x4E>(x);
  x += dppf<0x124>(x);
  x += dppf<0x128>(x);
  return x;
}

// ---------------- fused prep: all bf16 conversions + bias copy, one launch ----
__global__ void k_prep(const float* __restrict__ hidden, const float* __restrict__ Wq,
                       const float* __restrict__ Wk, const float* __restrict__ Wv,
                       const float* __restrict__ dist, const float* __restrict__ bq,
                       const float* __restrict__ bk, const float* __restrict__ bv,
                       ushort* __restrict__ Hbf, ushort* __restrict__ Wqkv,
                       ushort* __restrict__ Ebf, float* __restrict__ Bqkv) {
  int i = blockIdx.x * blockDim.x + threadIdx.x;
  const float* src; ushort* dst; int o;
  if (i < 1048576)      { src = hidden; o = i;            dst = Hbf; }
  else if (i < 1310720) { src = Wq;   o = i - 1048576;    dst = Wqkv; }
  else if (i < 1572864) { src = Wk;   o = i - 1310720;    dst = Wqkv + 1048576; }
  else if (i < 1835008) { src = Wv;   o = i - 1572864;    dst = Wqkv + 2097152; }
  else if (i < 1867760) { src = dist; o = i - 1835008;    dst = Ebf; }
  else if (i < 1868528) {
    int ib = i - 1867760;
    const float* bs = ib < 256 ? bq : (ib < 512 ? bk : bv);
    reinterpret_cast<float4*>(Bqkv)[ib] = reinterpret_cast<const float4*>(bs)[ib & 255];
    return;
  } else return;
  float4 v = reinterpret_cast<const float4*>(src)[o];
  ushort4 u;
  u.x = f2bf(v.x); u.y = f2bf(v.y); u.z = f2bf(v.z); u.w = f2bf(v.w);
  reinterpret_cast<ushort4*>(dst)[o] = u;
}

// ---------------- fused QKV projection GEMM (m97 structure + XCD swizzle) -----
__global__ __launch_bounds__(256) void k_gemm_qkv(
    const ushort* __restrict__ A, const ushort* __restrict__ W,
    const float* __restrict__ bias, ushort* __restrict__ C)
{
  __shared__ __align__(16) ushort As[128 * 32];
  __shared__ __align__(16) ushort Bs[128 * 32];
  // XCD-aware swizzle: 768 blocks, 8 XCDs, 96 per XCD (768%8==0, bijective)
  int linear = blockIdx.x + blockIdx.y * 24;
  int swzb = (linear & 7) * 96 + (linear >> 3);
  const int n0 = (swzb % 24) * 128;
  const int m0 = (swzb / 24) * 128;
  const int tid = threadIdx.x;
  const int w = tid >> 6, lane = tid & 63;
  const int wr = (w >> 1) * 64, wc = (w & 1) * 64;
  const int lr = lane & 15, lk = (lane >> 4) * 8;

  f32x4 acc[4][4] = {};

  for (int k0 = 0; k0 < 1024; k0 += 32) {
    __syncthreads();
#pragma unroll
    for (int inst = 0; inst < 2; ++inst) {
      int chunk = w * 128 + inst * 64 + lane;
      int row = chunk >> 2, c8 = (chunk & 3) * 8;
      __builtin_amdgcn_global_load_lds(
          (gv_t*)(A + (size_t)(m0 + row) * 1024 + k0 + c8),
          (lv_t*)(As + (size_t)(w * 128 + inst * 64) * 8), 16, 0, 0);
      __builtin_amdgcn_global_load_lds(
          (gv_t*)(W + (size_t)(n0 + row) * 1024 + k0 + c8),
          (lv_t*)(Bs + (size_t)(w * 128 + inst * 64) * 8), 16, 0, 0);
    }
    __syncthreads();
    short8 af[4], bfr[4];
#pragma unroll
    for (int t = 0; t < 4; ++t) {
      af[t]  = *reinterpret_cast<const short8*>(As + (wr + t * 16 + lr) * 32 + lk);
      bfr[t] = *reinterpret_cast<const short8*>(Bs + (wc + t * 16 + lr) * 32 + lk);
    }
#pragma unroll
    for (int mt = 0; mt < 4; ++mt)
#pragma unroll
      for (int nt = 0; nt < 4; ++nt)
        acc[mt][nt] = __builtin_amdgcn_mfma_f32_16x16x32_bf16(af[mt], bfr[nt], acc[mt][nt], 0, 0, 0);
  }

  float bv[4];
#pragma unroll
  for (int nt = 0; nt < 4; ++nt) bv[nt] = bias[n0 + wc + nt * 16 + lr];
#pragma unroll
  for (int mt = 0; mt < 4; ++mt)
#pragma unroll
    for (int nt = 0; nt < 4; ++nt)
#pragma unroll
      for (int j = 0; j < 4; ++j) {
        int row = m0 + wr + mt * 16 + (lane >> 4) * 4 + j;
        int col = n0 + wc + nt * 16 + lr;
        C[(size_t)row * 3072 + col] = f2bf(acc[mt][nt][j] + bv[nt]);
      }
}

// ---------------- V transpose: QKV V-slice -> VT[(b*16+h)*64 + d][l] ----------
__global__ __launch_bounds__(256) void k_vt(const ushort* __restrict__ QKV,
                                            ushort* __restrict__ VT) {
  __shared__ ushort t[64][65];
  const int bh = blockIdx.y, b = bh >> 4, h = bh & 15;
  const int l0 = blockIdx.x * 64;
  const int r = threadIdx.x >> 2, c0 = (threadIdx.x & 3) * 16;
  const ushort* src = QKV + (size_t)(b * 1024 + l0 + r) * 3072 + 2048 + h * 64 + c0;
  short8 v0 = *reinterpret_cast<const short8*>(src);
  short8 v1 = *reinterpret_cast<const short8*>(src + 8);
#pragma unroll
  for (int i = 0; i < 8; ++i) {
    t[c0 + i][r] = (ushort)v0[i];
    t[c0 + 8 + i][r] = (ushort)v1[i];
  }
  __syncthreads();
  short8 o0, o1;
#pragma unroll
  for (int i = 0; i < 8; ++i) {
    o0[i] = (short)t[r][c0 + i];
    o1[i] = (short)t[r][c0 + 8 + i];
  }
  ushort* dst = VT + (size_t)(bh * 64 + r) * 1024 + l0 + c0;
  *reinterpret_cast<short8*>(dst) = o0;
  *reinterpret_cast<short8*>(dst + 8) = o1;
}

// ---------------- fused attention, 2 l-tiles/block, 8 waves -------------------
// Round-12 kernel (139.7 us verified) + deferred rsum16: per-lane partial sums
// accumulate in the loop; the 16-lane DPP reduction happens once in epilogue
// (linearity makes this exact).
__global__ __launch_bounds__(512, 4) void k_attn(
    const ushort* __restrict__ QKV, const ushort* __restrict__ VTg,
    const ushort* __restrict__ E, const float* __restrict__ mask,
    float* __restrict__ out)
{
  __shared__ __align__(16) ushort Kl[64 * 64];     //  8 KB
  __shared__ __align__(16) ushort Vl[64 * 64];     //  8 KB
  __shared__ __align__(16) ushort El[256 * 64];    // 32 KB circular E window
  __shared__ __align__(16) ushort T2s[64 * 196];   // 24.5 KB; first 8192 elems alias P

  // XCD-aware swizzle: 512 blocks, 8 XCDs -> each XCD gets 8 full (b,h) panels
  int linear = blockIdx.x + (blockIdx.y << 3) + (blockIdx.z << 7);
  int swzb = (linear & 7) * 64 + (linear >> 3);
  const int lt = swzb & 7, h = (swzb >> 3) & 15, b = swzb >> 7;

  const int bh = b * 16 + h;
  const int l0 = lt * 128;
  const int tid = threadIdx.x;
  const int w = tid >> 6, lane = tid & 63;
  const int g = lane >> 4, m = lane & 15, g4 = g * 4;
  const int rsub = lane >> 3, csub = lane & 7;

  const ushort* Qg = QKV;
  const ushort* Kg = QKV + 1024;
  const float* maskrow = mask + b * 1024;

  // Q fragments (reused all r-tiles)
  short8 qf0, qf1;
  {
    const size_t qoff = (size_t)(b * 1024 + l0 + w * 16 + m) * 3072 + h * 64;
    qf0 = *reinterpret_cast<const short8*>(Qg + qoff + g * 8);
    qf1 = *reinterpret_cast<const short8*>(Qg + qoff + 32 + g * 8);
  }

  // hoisted T1-gather constants (round-3/4 verified)
  int srcl[4], bsel[4];
#pragma unroll
  for (int j = 0; j < 4; ++j) {
    int x = (g4 + j + 63 - m) & 15;
    srcl[j] = (lane & 48) | x;
    bsel[j] = (g4 + j) > x;
  }
  // T2 gather: elem addr = A0 + 3120*ct + j   (addr = (16ct+m)*196 + dd)
  const int A0 = 195 * m + 16 * w + g4 + 63;

  // ---- prologue staging: K tile 0, E window rows 0..191
  {
    int kr = w * 8 + rsub;
    __builtin_amdgcn_global_load_lds(
        (gv_t*)(Kg + (size_t)(b * 1024 + kr) * 3072 + h * 64 + ((csub ^ (kr & 7)) << 3)),
        (lv_t*)(Kl + w * 512), 16, 0, 0);
#pragma unroll
    for (int i = 0; i < 3; ++i) {
      int li = w * 3 + i;
      int er = li * 8 + rsub;
      int p = l0 + 960 + er; if (p > 2046) p = 2046;  // clamped row never gathered
      __builtin_amdgcn_global_load_lds(
          (gv_t*)(E + (size_t)p * 64 + ((csub ^ (er & 7)) << 3)),
          (lv_t*)(El + li * 512), 16, 0, 0);
    }
  }

  f32x4 o_[4] = {};
  float s_[4];
#pragma unroll
  for (int j = 0; j < 4; ++j) s_[j] = 0.f;

  int rot = 0;

  for (int rt = 0; rt < 16; ++rt) {
    const int r0 = rt * 64;
    __syncthreads();  // B1: K/E(cur) staged visible; Vl free (prev PV done)

    // V stage (cur) — drains at B2
    {
      int dr = w * 8 + rsub;
      __builtin_amdgcn_global_load_lds(
          (gv_t*)(VTg + (size_t)(bh * 64 + dr) * 1024 + r0 + ((csub ^ (dr & 7)) << 3)),
          (lv_t*)(Vl + w * 512), 16, 0, 0);
    }

    // E fragments for window tiles w (ea0) and w+4 (ea1); shared by T1 AND T2
    short8 ea0[2], ea1[2];
    {
      int row = w * 16 + m, phys = (row + rot) & 255;
      ea0[0] = *reinterpret_cast<const short8*>(El + phys * 64 + ((g ^ (row & 7)) << 3));
      ea0[1] = *reinterpret_cast<const short8*>(El + phys * 64 + (((g + 4) ^ (row & 7)) << 3));
    }
    {
      int row = (w + 4) * 16 + m, phys = (row + rot) & 255;
      ea1[0] = *reinterpret_cast<const short8*>(El + phys * 64 + ((g ^ (row & 7)) << 3));
      ea1[1] = *reinterpret_cast<const short8*>(El + phys * 64 + (((g + 4) ^ (row & 7)) << 3));
    }

    // QK^T + T2 (transposed-output) per f-tile.
    // T2 tiles: all waves -> tile w+4 (from ea1); waves 0-3 also tile w (ea0).
    f32x4 sc[4];
#pragma unroll
    for (int ft = 0; ft < 4; ++ft) {
      int kr = ft * 16 + m;
      short8 kb0 = *reinterpret_cast<const short8*>(Kl + kr * 64 + ((g ^ (kr & 7)) << 3));
      short8 kb1 = *reinterpret_cast<const short8*>(Kl + kr * 64 + (((g + 4) ^ (kr & 7)) << 3));
      f32x4 z = {0.f, 0.f, 0.f, 0.f};
      sc[ft] = __builtin_amdgcn_mfma_f32_16x16x32_bf16(qf1, kb1,
               __builtin_amdgcn_mfma_f32_16x16x32_bf16(qf0, kb0, z, 0, 0, 0), 0, 0, 0);
      {
        f32x4 t2 = __builtin_amdgcn_mfma_f32_16x16x32_bf16(ea1[1], kb1,
                   __builtin_amdgcn_mfma_f32_16x16x32_bf16(ea1[0], kb0, z, 0, 0, 0), 0, 0, 0);
        u32x2 pk;
        pk[0] = (unsigned)f2bf(t2[0]) | ((unsigned)f2bf(t2[1]) << 16);
        pk[1] = (unsigned)f2bf(t2[2]) | ((unsigned)f2bf(t2[3]) << 16);
        *reinterpret_cast<u32x2*>(T2s + (ft * 16 + m) * 196 + (w + 4) * 16 + g4) = pk;
      }
      if (w < 4) {
        f32x4 t2 = __builtin_amdgcn_mfma_f32_16x16x32_bf16(ea0[1], kb1,
                   __builtin_amdgcn_mfma_f32_16x16x32_bf16(ea0[0], kb0, z, 0, 0, 0), 0, 0, 0);
        u32x2 pk;
        pk[0] = (unsigned)f2bf(t2[0]) | ((unsigned)f2bf(t2[1]) << 16);
        pk[1] = (unsigned)f2bf(t2[2]) | ((unsigned)f2bf(t2[3]) << 16);
        *reinterpret_cast<u32x2*>(T2s + (ft * 16 + m) * 196 + w * 16 + g4) = pk;
      }
    }

    // T1 local-window frags (dd in [16w, 16w+79)); tiles 0,4 reuse ea0/ea1
    f32x4 t1loc[5];
    {
      f32x4 z = {0.f, 0.f, 0.f, 0.f};
      t1loc[0] = __builtin_amdgcn_mfma_f32_16x16x32_bf16(qf1, ea0[1],
                 __builtin_amdgcn_mfma_f32_16x16x32_bf16(qf0, ea0[0], z, 0, 0, 0), 0, 0, 0);
      t1loc[4] = __builtin_amdgcn_mfma_f32_16x16x32_bf16(qf1, ea1[1],
                 __builtin_amdgcn_mfma_f32_16x16x32_bf16(qf0, ea1[0], z, 0, 0, 0), 0, 0, 0);
    }
#pragma unroll
    for (int lti = 1; lti < 4; ++lti) {
      int row = (w + lti) * 16 + m, phys = (row + rot) & 255;
      short8 e0 = *reinterpret_cast<const short8*>(El + phys * 64 + ((g ^ (row & 7)) << 3));
      short8 e1 = *reinterpret_cast<const short8*>(El + phys * 64 + (((g + 4) ^ (row & 7)) << 3));
      f32x4 z = {0.f, 0.f, 0.f, 0.f};
      t1loc[lti] = __builtin_amdgcn_mfma_f32_16x16x32_bf16(qf1, e1,
                   __builtin_amdgcn_mfma_f32_16x16x32_bf16(qf0, e0, z, 0, 0, 0), 0, 0, 0);
    }

    __syncthreads();  // B2: T2s + Vl visible; Kl/El phase-1 readers done

    // stage next K tile + next 64 E rows (dest rows disjoint from live window)
    if (rt < 15) {
      int kr = w * 8 + rsub;
      __builtin_amdgcn_global_load_lds(
          (gv_t*)(Kg + (size_t)(b * 1024 + r0 + 64 + kr) * 3072 + h * 64 + ((csub ^ (kr & 7)) << 3)),
          (lv_t*)(Kl + w * 512), 16, 0, 0);
      int X = (rot + 192) & 255;
      int er = w * 8 + rsub;
      int p = l0 + 960 - 64 * (rt + 1) + er;  // in [0,1855], no clamp needed
      __builtin_amdgcn_global_load_lds(
          (gv_t*)(E + (size_t)p * 64 + ((csub ^ (er & 7)) << 3)),
          (lv_t*)(El + (X + w * 8) * 64), 16, 0, 0);
    }

    // S assembly + fixed-max softmax via exp2:
    // P = exp2((sc+t1+t2)*0.125*log2e + mk*log2e)
    float sv[4][4];
    const float SCL = 0.18033688f;  // 0.125 * log2(e)
#pragma unroll
    for (int ct = 0; ct < 4; ++ct) {
      float mkl = maskrow[r0 + ct * 16 + m] * 1.4426950f;
#pragma unroll
      for (int j = 0; j < 4; ++j) {
        float t2v = bf2f(T2s[A0 + 3120 * ct + j]);
        float val = bsel[j] ? t1loc[4 - ct][j] : t1loc[3 - ct][j];
        float t1v = __shfl(val, srcl[j]);
        sv[ct][j] = __builtin_amdgcn_exp2f((sc[ct][j] + t1v + t2v) * SCL + mkl);
      }
    }
    // deferred reduction: accumulate per-lane partials; rsum16 once in epilogue
#pragma unroll
    for (int j = 0; j < 4; ++j)
      s_[j] += sv[0][j] + sv[1][j] + sv[2][j] + sv[3][j];

    __syncthreads();  // B2.5: all waves' T2s gather reads complete — alias safe

    // P -> LDS (alias over T2s), row-major [e][f] with chunk XOR swizzle
    ushort* Pp = (ushort*)T2s;
#pragma unroll
    for (int ct = 0; ct < 4; ++ct)
#pragma unroll
      for (int j = 0; j < 4; ++j) {
        int e = g4 + j;
        int f = ct * 16 + m;
        Pp[w * 1024 + e * 64 + ((((f >> 3) ^ (e & 7)) << 3) | (f & 7))] = f2bf(sv[ct][j]);
      }

    // PV: A = P rows (b128), B = V^T rows (b128)
    {
      short8 pf0 = *reinterpret_cast<const short8*>(Pp + w * 1024 + m * 64 + ((g ^ (m & 7)) << 3));
      short8 pf1 = *reinterpret_cast<const short8*>(Pp + w * 1024 + m * 64 + (((g + 4) ^ (m & 7)) << 3));
#pragma unroll
      for (int vt = 0; vt < 4; ++vt) {
        int dr = vt * 16 + m;
        short8 vb0 = *reinterpret_cast<const short8*>(Vl + dr * 64 + ((g ^ (dr & 7)) << 3));
        short8 vb1 = *reinterpret_cast<const short8*>(Vl + dr * 64 + (((g + 4) ^ (dr & 7)) << 3));
        o_[vt] = __builtin_amdgcn_mfma_f32_16x16x32_bf16(pf0, vb0, o_[vt], 0, 0, 0);
        o_[vt] = __builtin_amdgcn_mfma_f32_16x16x32_bf16(pf1, vb1, o_[vt], 0, 0, 0);
      }
    }

    rot = (rot + 192) & 255;
  }

  // epilogue: O / s  (single DPP reduction per j)
#pragma unroll
  for (int j = 0; j < 4; ++j) {
    float inv = 1.0f / rsum16(s_[j]);
    int row = b * 1024 + l0 + w * 16 + g4 + j;
#pragma unroll
    for (int vt = 0; vt < 4; ++vt)
      out[(size_t)row * 1024 + h * 64 + vt * 16 + m] = o_[vt][j] * inv;
  }
}

// ---------------- host launch ----------------
extern "C" void kernel_launch(void* const* d_in, const int* in_sizes, int n_in,
                              void* d_out, int out_size, void* d_ws, size_t ws_size,
                              hipStream_t stream) {
  const float* hidden = (const float*)d_in[0];
  const float* mask   = (const float*)d_in[1];
  const float* Wq = (const float*)d_in[2];
  const float* bq = (const float*)d_in[3];
  const float* Wk = (const float*)d_in[4];
  const float* bk = (const float*)d_in[5];
  const float* Wv = (const float*)d_in[6];
  const float* bv = (const float*)d_in[7];
  const float* dist = (const float*)d_in[8];
  float* out = (float*)d_out;

  char* ws = (char*)d_ws;
  ushort* Hbf  = (ushort*)(ws);                                      //  8,388,608 (reused as VT)
  ushort* Wqkv = (ushort*)(ws + 8388608);                            //  6,291,456
  float*  Bqkv = (float*) (ws + 8388608 + 6291456);                  //     16,384
  ushort* Ebf  = (ushort*)(ws + 8388608 + 6291456 + 16384);          //    262,144
  ushort* QKV  = (ushort*)(ws + 8388608 + 6291456 + 16384 + 262144); // 25,165,824
  ushort* VT   = Hbf;  // V^T [(b*16+h)*64 + d][l]

  k_prep<<<7299, 256, 0, stream>>>(hidden, Wq, Wk, Wv, dist, bq, bk, bv,
                                   Hbf, Wqkv, Ebf, Bqkv);
  k_gemm_qkv<<<dim3(24, 32), 256, 0, stream>>>(Hbf, Wqkv, Bqkv, QKV);
  k_vt<<<dim3(16, 64), 256, 0, stream>>>(QKV, VT);
  k_attn<<<dim3(8, 16, 4), 512, 0, stream>>>(QKV, VT, Ebf, mask, out);
}